// Round 1
// 848.200 us; speedup vs baseline: 1.0854x; 1.0854x over previous
//
#include <hip/hip_runtime.h>
#include <hip/hip_bf16.h>
#include <math.h>

#define N_USERS 50000
#define N_ITEMS 30000
#define N_ENT   100000
#define NE      500000      // KG edges E
#define NEI     1000000     // interaction edges EI
#define D       64
#define GAMMA   0.2f

#define UBK ((N_USERS + 255) / 256)   // 196 user buckets (256 users each)
#define HBK ((N_ENT + 255) / 256)     // 391 head buckets (256 heads each)
#define PCHUNK 4096                   // edges per pass-1 block

typedef __hip_bfloat16 bf16;

__device__ __forceinline__ float wave_sum(float v) {
    #pragma unroll
    for (int off = 32; off > 0; off >>= 1) v += __shfl_xor(v, off, 64);
    return v;
}

__device__ __forceinline__ float g16_sum(float v) {
    #pragma unroll
    for (int off = 1; off < 16; off <<= 1) v += __shfl_xor(v, off, 64);
    return v;
}

__device__ __forceinline__ float bits2f(unsigned short u) {
    return __uint_as_float(((unsigned)u) << 16);
}

__device__ __forceinline__ unsigned short f2bf_bits(float f) {
    bf16 b = __float2bfloat16(f);
    return *(unsigned short*)&b;
}

__device__ __forceinline__ float sigmoidf(float x) { return 1.0f / (1.0f + expf(-x)); }

__device__ __forceinline__ float n2n(float y) {
    if (isnan(y)) return 0.0f;
    if (isinf(y)) return y > 0.0f ? 1e4f : 1e-4f;
    return y;
}

// ================= CSR build: bucketed 2-pass multisplit =================
// Bucket = id>>8. Pass-1 writes block-local contiguous runs per bucket (L2-merged
// within one XCD). Pass-2: one block per bucket, destination region <=41KB so all
// partial-line writes merge in that block's XCD L2. Per-user/head CSR offsets are
// produced inside pass-2 (LDS count + scan), eliminating the global histogram +
// 3-kernel scan chain of the previous version.

// per-bucket histogram (LDS-aggregated)
__global__ __launch_bounds__(256) void k_histb(const int* __restrict__ ie,
        const int* __restrict__ eidx, int* __restrict__ bcntU,
        int* __restrict__ bcntH, int UCH) {
    __shared__ int lc[HBK + 1];
    int t = threadIdx.x;
    int b = blockIdx.x;
    for (int i = t; i < HBK + 1; i += 256) lc[i] = 0;
    __syncthreads();
    if (b < UCH) {
        int base = b * PCHUNK;
        #pragma unroll
        for (int i = 0; i < PCHUNK / 256; i++) {
            int e = base + i * 256 + t;
            if (e < NEI) atomicAdd(&lc[ie[e] >> 8], 1);
        }
        __syncthreads();
        for (int i = t; i < UBK; i += 256) if (lc[i]) atomicAdd(&bcntU[i], lc[i]);
    } else {
        int base = (b - UCH) * PCHUNK;
        #pragma unroll
        for (int i = 0; i < PCHUNK / 256; i++) {
            int e = base + i * 256 + t;
            if (e < NE) atomicAdd(&lc[eidx[e] >> 8], 1);
        }
        __syncthreads();
        for (int i = t; i < HBK; i += 256) if (lc[i]) atomicAdd(&bcntH[i], lc[i]);
    }
}

// scan bucket counts -> bucket offsets + init bucket cursors; set sentinel offsets
__global__ void k_scanb(const int* __restrict__ bcntU, int* __restrict__ bOffU,
                        int* __restrict__ bcurU, const int* __restrict__ bcntH,
                        int* __restrict__ bOffH, int* __restrict__ bcurH,
                        int* __restrict__ offU, int* __restrict__ offH) {
    __shared__ int sh[512];
    int t = threadIdx.x;
    const int* c; int* o; int* cu; int n; int tot;
    if (blockIdx.x == 0) { c = bcntU; o = bOffU; cu = bcurU; n = UBK; tot = NEI; }
    else                 { c = bcntH; o = bOffH; cu = bcurH; n = HBK; tot = NE; }
    int v = (t < n) ? c[t] : 0;
    sh[t] = v;
    __syncthreads();
    for (int d = 1; d < 512; d <<= 1) {
        int x = (t >= d) ? sh[t - d] : 0;
        __syncthreads();
        sh[t] += x;
        __syncthreads();
    }
    if (t < n) { int ex = sh[t] - v; o[t] = ex; cu[t] = ex; }
    if (t == 0) {
        o[n] = tot;
        if (blockIdx.x == 0) offU[N_USERS] = NEI;
        else                 offH[N_ENT] = NE;
    }
}

// pass 1: partition edges into buckets, block-local contiguous runs.
// staged word packs local id (8 bits) into the top byte.
__global__ __launch_bounds__(256) void k_part1(const int* __restrict__ ie,
        const float* __restrict__ w, const int* __restrict__ eidx,
        const int* __restrict__ etype, int* __restrict__ bcurU,
        int* __restrict__ bcurH, int2* __restrict__ stIW,
        int* __restrict__ stTR, int UCH) {
    __shared__ int lcnt[HBK + 1];
    __shared__ int lbase[HBK + 1];
    int t = threadIdx.x;
    int b = blockIdx.x;
    for (int i = t; i < HBK + 1; i += 256) lcnt[i] = 0;
    __syncthreads();
    if (b < UCH) {
        int base = b * PCHUNK;
        int bkt[PCHUNK / 256], rnk[PCHUNK / 256];
        #pragma unroll
        for (int i = 0; i < PCHUNK / 256; i++) {
            int e = base + i * 256 + t;
            bkt[i] = -1;
            rnk[i] = 0;
            if (e < NEI) {
                int k = ie[e] >> 8;
                bkt[i] = k;
                rnk[i] = atomicAdd(&lcnt[k], 1);
            }
        }
        __syncthreads();
        for (int i = t; i < UBK; i += 256)
            if (lcnt[i] > 0) lbase[i] = atomicAdd(&bcurU[i], lcnt[i]);
        __syncthreads();
        #pragma unroll
        for (int i = 0; i < PCHUNK / 256; i++) {
            int e = base + i * 256 + t;
            if (bkt[i] >= 0) {
                int pos = lbase[bkt[i]] + rnk[i];
                int ul = ie[e] & 255;
                stIW[pos] = make_int2(ie[NEI + e] | (ul << 24), __float_as_int(w[e]));
            }
        }
    } else {
        int base = (b - UCH) * PCHUNK;
        int bkt[PCHUNK / 256], rnk[PCHUNK / 256];
        #pragma unroll
        for (int i = 0; i < PCHUNK / 256; i++) {
            int e = base + i * 256 + t;
            bkt[i] = -1;
            rnk[i] = 0;
            if (e < NE) {
                int k = eidx[e] >> 8;
                bkt[i] = k;
                rnk[i] = atomicAdd(&lcnt[k], 1);
            }
        }
        __syncthreads();
        for (int i = t; i < HBK; i += 256)
            if (lcnt[i] > 0) lbase[i] = atomicAdd(&bcurH[i], lcnt[i]);
        __syncthreads();
        #pragma unroll
        for (int i = 0; i < PCHUNK / 256; i++) {
            int e = base + i * 256 + t;
            if (bkt[i] >= 0) {
                int pos = lbase[bkt[i]] + rnk[i];
                int hl = eidx[e] & 255;
                stTR[pos] = eidx[NE + e] | ((etype[e] - 1) << 20) | (hl << 24);
            }
        }
    }
}

// pass 2: one block per bucket. Count per-id in LDS, scan -> per-id CSR offsets,
// then scatter within the bucket's private destination region.
__global__ __launch_bounds__(256) void k_part2(const int* __restrict__ bOffU,
        const int2* __restrict__ stIW, int* __restrict__ offU,
        int2* __restrict__ csr_itw, const int* __restrict__ bOffH,
        const int* __restrict__ stTR, int* __restrict__ offH,
        int* __restrict__ csr_tr, int UBKc) {
    __shared__ int lcnt[256];
    __shared__ int lcur[256];
    int t = threadIdx.x;
    int b = blockIdx.x;
    lcnt[t] = 0;
    __syncthreads();
    if (b < UBKc) {
        int s = bOffU[b], e = bOffU[b + 1];
        for (int j = s + t; j < e; j += 256)
            atomicAdd(&lcnt[((unsigned)stIW[j].x) >> 24], 1);
        __syncthreads();
        int v = lcnt[t];
        lcur[t] = v;
        __syncthreads();
        for (int d = 1; d < 256; d <<= 1) {
            int x = (t >= d) ? lcur[t - d] : 0;
            __syncthreads();
            lcur[t] += x;
            __syncthreads();
        }
        int base = s + lcur[t] - v;          // exclusive within bucket
        int u = (b << 8) + t;
        if (u < N_USERS) offU[u] = base;
        __syncthreads();
        lcur[t] = base;
        __syncthreads();
        for (int j = s + t; j < e; j += 256) {
            int2 r = stIW[j];
            int pos = atomicAdd(&lcur[((unsigned)r.x) >> 24], 1);
            csr_itw[pos] = make_int2(r.x & 0x00FFFFFF, r.y);
        }
    } else {
        int bb = b - UBKc;
        int s = bOffH[bb], e = bOffH[bb + 1];
        for (int j = s + t; j < e; j += 256)
            atomicAdd(&lcnt[((unsigned)stTR[j]) >> 24], 1);
        __syncthreads();
        int v = lcnt[t];
        lcur[t] = v;
        __syncthreads();
        for (int d = 1; d < 256; d <<= 1) {
            int x = (t >= d) ? lcur[t - d] : 0;
            __syncthreads();
            lcur[t] += x;
            __syncthreads();
        }
        int base = s + lcur[t] - v;
        int h = (bb << 8) + t;
        if (h < N_ENT) offH[h] = base;
        __syncthreads();
        lcur[t] = base;
        __syncthreads();
        for (int j = s + t; j < e; j += 256) {
            int r = stTR[j];
            int pos = atomicAdd(&lcur[((unsigned)r) >> 24], 1);
            csr_tr[pos] = r & 0x00FFFFFF;   // keep t (20b) + rel (bits 20-23)
        }
    }
}

// ================= lane-owns-row tiled GEMM helpers =================
__device__ __forceinline__ void stage_rows2(const float* __restrict__ s0,
                                            const float* __restrict__ s1,
                                            float* At, int row0, int n, int t) {
    #pragma unroll
    for (int half = 0; half < 2; half++) {
        const float* src = half ? s1 : s0;
        int kofs = half ? 32 : 0;
        #pragma unroll
        for (int fi = t, it = 0; it < 2; fi += 256, it++) {
            int row = fi >> 3;
            int k4 = (fi & 7) << 2;
            float4 v = make_float4(0.f, 0.f, 0.f, 0.f);
            if (row0 + row < n) v = *(const float4*)&src[(size_t)(row0 + row) * 32 + k4];
            At[(kofs + k4 + 0) * 64 + row] = v.x;
            At[(kofs + k4 + 1) * 64 + row] = v.y;
            At[(kofs + k4 + 2) * 64 + row] = v.z;
            At[(kofs + k4 + 3) * 64 + row] = v.w;
        }
    }
}

__device__ __forceinline__ void stage_rows1(const float* __restrict__ src,
                                            float* At, int row0, int n, int t) {
    #pragma unroll
    for (int fi = t, it = 0; it < 4; fi += 256, it++) {
        int row = fi >> 4;
        int k4 = (fi & 15) << 2;
        float4 v = make_float4(0.f, 0.f, 0.f, 0.f);
        if (row0 + row < n) v = *(const float4*)&src[(size_t)(row0 + row) * 64 + k4];
        At[(k4 + 0) * 64 + row] = v.x;
        At[(k4 + 1) * 64 + row] = v.y;
        At[(k4 + 2) * 64 + row] = v.z;
        At[(k4 + 3) * 64 + row] = v.w;
    }
}

// fused: blocks [0,IB) item proj (Ik bf16 + Iv), [IB, IB+UB) user proj (Uq)
__global__ __launch_bounds__(256) void k_proj(const float* __restrict__ I,
        const float* __restrict__ Wk, const float* __restrict__ Wv,
        const float* __restrict__ UE, const float* __restrict__ Wq,
        bf16* __restrict__ IkB, float* __restrict__ Iv, float* __restrict__ Uq, int IB) {
    __shared__ float At[64 * 64];
    int t = threadIdx.x;
    int b = blockIdx.x;
    int lane = t & 63;
    int wv = __builtin_amdgcn_readfirstlane(t >> 6);
    if (b < IB) {
        int row0 = b << 6;
        stage_rows1(I, At, row0, N_ITEMS, t);
        __syncthreads();
        const float* Wb = ((wv >> 1) ? Wv : Wk) + (wv & 1) * 32;
        float acc[32];
        #pragma unroll
        for (int c = 0; c < 32; c++) acc[c] = 0.f;
        for (int k = 0; k < 64; k++) {
            float a = At[k * 64 + lane];
            const float* wr = Wb + k * 64;
            #pragma unroll
            for (int c4 = 0; c4 < 8; c4++) {
                float4 w4 = *(const float4*)&wr[c4 * 4];
                acc[c4 * 4 + 0] += a * w4.x;
                acc[c4 * 4 + 1] += a * w4.y;
                acc[c4 * 4 + 2] += a * w4.z;
                acc[c4 * 4 + 3] += a * w4.w;
            }
        }
        int row = row0 + lane;
        if (row < N_ITEMS) {
            if (wv >> 1) {
                float* dst = Iv + (size_t)row * 64 + (wv & 1) * 32;
                #pragma unroll
                for (int c4 = 0; c4 < 8; c4++)
                    *(float4*)&dst[c4 * 4] = make_float4(acc[c4*4], acc[c4*4+1], acc[c4*4+2], acc[c4*4+3]);
            } else {
                bf16* dst = IkB + (size_t)row * 64 + (wv & 1) * 32;
                #pragma unroll
                for (int c4 = 0; c4 < 8; c4++) {
                    ushort4 s;
                    s.x = f2bf_bits(acc[c4 * 4 + 0]);
                    s.y = f2bf_bits(acc[c4 * 4 + 1]);
                    s.z = f2bf_bits(acc[c4 * 4 + 2]);
                    s.w = f2bf_bits(acc[c4 * 4 + 3]);
                    *(ushort4*)&dst[c4 * 4] = s;
                }
            }
        }
    } else {
        int row0 = (b - IB) << 6;
        stage_rows1(UE, At, row0, N_USERS, t);
        __syncthreads();
        const float* Wb = Wq + wv * 16;
        float acc[16];
        #pragma unroll
        for (int c = 0; c < 16; c++) acc[c] = 0.f;
        for (int k = 0; k < 64; k++) {
            float a = At[k * 64 + lane];
            const float* wr = Wb + k * 64;
            #pragma unroll
            for (int c4 = 0; c4 < 4; c4++) {
                float4 w4 = *(const float4*)&wr[c4 * 4];
                acc[c4 * 4 + 0] += a * w4.x;
                acc[c4 * 4 + 1] += a * w4.y;
                acc[c4 * 4 + 2] += a * w4.z;
                acc[c4 * 4 + 3] += a * w4.w;
            }
        }
        int row = row0 + lane;
        if (row < N_USERS) {
            float* dst = Uq + (size_t)row * 64 + wv * 16;
            #pragma unroll
            for (int c4 = 0; c4 < 4; c4++)
                *(float4*)&dst[c4 * 4] = make_float4(acc[c4*4], acc[c4*4+1], acc[c4*4+2], acc[c4*4+3]);
        }
    }
}

// ================= Stage A edge kernels (two dispatches — NO fences) =================
__global__ void k_userA(const int* __restrict__ offU, const int2* __restrict__ itw,
                        const float* __restrict__ Uq, const bf16* __restrict__ IkB,
                        float* __restrict__ exA, float* __restrict__ denU, int n) {
    int u = (blockIdx.x * blockDim.x + threadIdx.x) >> 6;
    int lane = threadIdx.x & 63;
    if (u >= n) return;
    int s = offU[u], e = offU[u + 1];
    if (s == e) return;
    int l = lane & 15, g = lane >> 4;
    float4 qv = *(const float4*)&Uq[(size_t)u * D + l * 4];
    float den = 0.f;
    for (int j0 = s; j0 < e; j0 += 4) {
        int j = j0 + g;
        bool valid = j < e;
        int jj = valid ? j : s;
        int2 iw = itw[jj];
        ushort4 ik = *(const ushort4*)&IkB[(size_t)iw.x * D + l * 4];
        float d = qv.x * bits2f(ik.x) + qv.y * bits2f(ik.y) +
                  qv.z * bits2f(ik.z) + qv.w * bits2f(ik.w);
        float sc = g16_sum(d);
        float ex = valid ? expf(sc * 0.125f * __int_as_float(iw.y)) : 0.f;
        den += ex;
        if (valid && l == 0) exA[j] = ex;
    }
    den += __shfl_xor(den, 16, 64);
    den += __shfl_xor(den, 32, 64);
    if (lane == 0) denU[u] = den * (float)(e - s);  // den * deg
}

__global__ void k_userB(const int* __restrict__ offU, const int2* __restrict__ itw,
                        const float* __restrict__ exA, const float* __restrict__ denU,
                        float* __restrict__ c, int n) {
    int u = (blockIdx.x * blockDim.x + threadIdx.x) >> 6;
    int lane = threadIdx.x & 63;
    if (u >= n) return;
    int s = offU[u], e = offU[u + 1];
    if (s == e) return;
    float inv = 1.0f / denU[u];
    for (int j = s + lane; j < e; j += 64)
        atomicAdd(&c[itw[j].x], exA[j] * inv);
}

__global__ void k_pdense(const float* __restrict__ c, const float* __restrict__ Iv,
                         float* __restrict__ p, int n) {
    int lane = threadIdx.x & 63;
    int gw = blockIdx.x * 4 + (threadIdx.x >> 6);
    int nw = gridDim.x * 4;
    float acc = 0.f;
    for (int i = gw; i < n; i += nw) acc += c[i] * Iv[(size_t)i * D + lane];
    __shared__ float red[256];
    red[threadIdx.x] = acc;
    __syncthreads();
    if (threadIdx.x < 64) {
        float s = red[threadIdx.x] + red[threadIdx.x + 64] + red[threadIdx.x + 128] + red[threadIdx.x + 192];
        atomicAdd(&p[threadIdx.x], s);
    }
}

// ================= Stage B: ent_ab + rel_tables + v2 in one dispatch =================
__global__ __launch_bounds__(256) void k_entabx(const float* __restrict__ er,
        const float* __restrict__ ei, const float* __restrict__ fpW1,
        const float* __restrict__ rr, const float* __restrict__ ri,
        const float* __restrict__ rtW1, const float* __restrict__ rtW2,
        const float* __restrict__ rt_b2, const float* __restrict__ p,
        float* __restrict__ EH, float* __restrict__ ET,
        float* __restrict__ RR1, float* __restrict__ PSI,
        float* __restrict__ v2, float* __restrict__ cb, int EB) {
    __shared__ float At[64 * 64];
    int b = blockIdx.x;
    int t = threadIdx.x;
    if (b < EB) {
        int row0 = b << 6;
        stage_rows2(er, ei, At, row0, N_ENT, t);
        __syncthreads();
        int lane = t & 63;
        int wv = __builtin_amdgcn_readfirstlane(t >> 6);
        const float* Wb = fpW1 + ((wv >> 1) ? (128 * 64) : 0) + (wv & 1) * 32;
        float acc[32];
        #pragma unroll
        for (int c = 0; c < 32; c++) acc[c] = 0.f;
        for (int k = 0; k < 64; k++) {
            float a = At[k * 64 + lane];
            const float* wr = Wb + k * 64;
            #pragma unroll
            for (int c4 = 0; c4 < 8; c4++) {
                float4 w4 = *(const float4*)&wr[c4 * 4];
                acc[c4 * 4 + 0] += a * w4.x;
                acc[c4 * 4 + 1] += a * w4.y;
                acc[c4 * 4 + 2] += a * w4.z;
                acc[c4 * 4 + 3] += a * w4.w;
            }
        }
        int row = row0 + lane;
        if (row < N_ENT) {
            float* dst = ((wv >> 1) ? ET : EH) + (size_t)row * 64 + (wv & 1) * 32;
            #pragma unroll
            for (int c4 = 0; c4 < 8; c4++)
                *(float4*)&dst[c4 * 4] = make_float4(acc[c4*4], acc[c4*4+1], acc[c4*4+2], acc[c4*4+3]);
        }
    } else if (b == EB) {
        if (t < 64) {
            int lane = t;
            for (int r = 0; r < 10; r++) {
                float a = 0.f, bb = 0.f;
                for (int k = 0; k < 32; k++) {
                    float sr = rr[r * 32 + k], si = ri[r * 32 + k];
                    a  += sr * fpW1[(64 + k) * D + lane] + si * fpW1[(96 + k) * D + lane];
                    bb += sr * rtW1[k * D + lane] + si * rtW1[(32 + k) * D + lane];
                }
                RR1[r * D + lane] = a;
                PSI[r * D + lane] = bb;
            }
        }
    } else {
        if (t < 64) {
            int j = t;
            float acc = 0.f;
            #pragma unroll
            for (int k = 0; k < D; k++) acc += rtW2[j * D + k] * p[k];
            v2[j] = acc;
            float cc = rt_b2[j] * p[j];
            cc = wave_sum(cc);
            if (j == 0) cb[0] = cc;
        }
    }
}

// PHI = [er|ei]@rtW1
__global__ __launch_bounds__(256) void k_ent_phi(const float* __restrict__ er,
        const float* __restrict__ ei, const float* __restrict__ rtW1,
        float* __restrict__ PHI, int n) {
    __shared__ float At[64 * 64];
    int t = threadIdx.x;
    int row0 = blockIdx.x << 6;
    stage_rows2(er, ei, At, row0, n, t);
    __syncthreads();
    int lane = t & 63;
    int wv = __builtin_amdgcn_readfirstlane(t >> 6);
    const float* Wb = rtW1 + wv * 16;
    float acc[16];
    #pragma unroll
    for (int c = 0; c < 16; c++) acc[c] = 0.f;
    for (int k = 0; k < 64; k++) {
        float a = At[k * 64 + lane];
        const float* wr = Wb + k * 64;
        #pragma unroll
        for (int c4 = 0; c4 < 4; c4++) {
            float4 w4 = *(const float4*)&wr[c4 * 4];
            acc[c4 * 4 + 0] += a * w4.x;
            acc[c4 * 4 + 1] += a * w4.y;
            acc[c4 * 4 + 2] += a * w4.z;
            acc[c4 * 4 + 3] += a * w4.w;
        }
    }
    int row = row0 + lane;
    if (row < n) {
        float* dst = PHI + (size_t)row * 64 + wv * 16;
        #pragma unroll
        for (int c4 = 0; c4 < 4; c4++)
            *(float4*)&dst[c4 * 4] = make_float4(acc[c4*4], acc[c4*4+1], acc[c4*4+2], acc[c4*4+3]);
    }
}

// wave/head, 16-lane subgroups, 4 edges in flight: gate weights
__global__ void k_omega1(const int* __restrict__ offH, const int* __restrict__ csr_tr,
                         const float* __restrict__ EH, const float* __restrict__ ET,
                         const float* __restrict__ RR1, const float* __restrict__ fp_b1,
                         const float* __restrict__ fpW2, const float* __restrict__ fp_b2,
                         float* __restrict__ w0a, float* __restrict__ w1a,
                         float* __restrict__ w2a, int n) {
    int h = (blockIdx.x * blockDim.x + threadIdx.x) >> 6;
    int lane = threadIdx.x & 63;
    if (h >= n) return;
    int s = offH[h], e = offH[h + 1];
    if (s == e) return;
    int l = lane & 15, g = lane >> 4;
    int d0 = l * 4;
    float4 ehh = *(const float4*)&EH[(size_t)h * D + d0];
    float4 b1 = *(const float4*)&fp_b1[d0];
    ehh.x += b1.x; ehh.y += b1.y; ehh.z += b1.z; ehh.w += b1.w;
    float f0[4], f1[4], f2[4];
    #pragma unroll
    for (int cc = 0; cc < 4; cc++) {
        f0[cc] = fpW2[(d0 + cc) * 3 + 0];
        f1[cc] = fpW2[(d0 + cc) * 3 + 1];
        f2[cc] = fpW2[(d0 + cc) * 3 + 2];
    }
    float b20 = fp_b2[0], b21 = fp_b2[1], b22 = fp_b2[2];
    for (int j0 = s; j0 < e; j0 += 4) {
        int j = j0 + g;
        bool valid = j < e;
        int jj = valid ? j : s;
        int pk = csr_tr[jj];
        int t = pk & 0xFFFFF, r = pk >> 20;
        float4 et = *(const float4*)&ET[(size_t)t * D + d0];
        float4 rr = *(const float4*)&RR1[r * D + d0];
        float z0 = sigmoidf(ehh.x + rr.x + et.x);
        float z1 = sigmoidf(ehh.y + rr.y + et.y);
        float z2 = sigmoidf(ehh.z + rr.z + et.z);
        float z3 = sigmoidf(ehh.w + rr.w + et.w);
        float a0 = z0 * f0[0] + z1 * f0[1] + z2 * f0[2] + z3 * f0[3];
        float a1 = z0 * f1[0] + z1 * f1[1] + z2 * f1[2] + z3 * f1[3];
        float a2 = z0 * f2[0] + z1 * f2[1] + z2 * f2[2] + z3 * f2[3];
        a0 = g16_sum(a0); a1 = g16_sum(a1); a2 = g16_sum(a2);
        if (valid && l == 0) {
            a0 += b20; a1 += b21; a2 += b22;
            float mx = fmaxf(a0, fmaxf(a1, a2));
            float e0 = expf(a0 - mx), e1 = expf(a1 - mx), e2 = expf(a2 - mx);
            float inv = 1.0f / (e0 + e1 + e2);
            w0a[j] = e0 * inv;
            w1a[j] = e1 * inv;
            w2a[j] = e2 * inv;
        }
    }
}

// omega + segO (wave-local) with cvt blocks appended; NO fence
__global__ void k_omega2a(const int* __restrict__ offH, const int* __restrict__ csr_tr,
                          const float* __restrict__ PHI, const float* __restrict__ PSI,
                          const float* __restrict__ rt_b1, const float* __restrict__ v2,
                          const float* __restrict__ cb, const float* __restrict__ w0a,
                          const float* __restrict__ w1a, const float* __restrict__ w2a,
                          float* __restrict__ omg, float* __restrict__ segO,
                          const float* __restrict__ src_emb, bf16* __restrict__ eA,
                          int OB, int n) {
    int b = blockIdx.x;
    if (b >= OB) {
        int base = (b - OB) * 1024 + threadIdx.x * 4;
        float4 v = *(const float4*)&src_emb[base];
        ushort4 s;
        s.x = f2bf_bits(v.x); s.y = f2bf_bits(v.y);
        s.z = f2bf_bits(v.z); s.w = f2bf_bits(v.w);
        *(ushort4*)&eA[base] = s;
        return;
    }
    int h = (b * blockDim.x + threadIdx.x) >> 6;
    int lane = threadIdx.x & 63;
    if (h >= n) return;
    int s = offH[h], e = offH[h + 1];
    if (s == e) return;
    int l = lane & 15, g = lane >> 4;
    int d0 = l * 4;
    float4 phh = *(const float4*)&PHI[(size_t)h * D + d0];
    float4 rb = *(const float4*)&rt_b1[d0];
    float4 vv = *(const float4*)&v2[d0];
    float cc = cb[0];
    float so = 0.f;
    for (int j0 = s; j0 < e; j0 += 4) {
        int j = j0 + g;
        bool valid = j < e;
        int jj = valid ? j : s;
        int pk = csr_tr[jj];
        int t = pk & 0xFFFFF, r = pk >> 20;
        float W0 = w0a[jj], W1 = w1a[jj], W2 = w2a[jj];
        float4 pt = *(const float4*)&PHI[(size_t)t * D + d0];
        float4 ps = *(const float4*)&PSI[r * D + d0];
        float sv = sigmoidf(W0 * phh.x + W1 * ps.x + W2 * pt.x + rb.x) * vv.x
                 + sigmoidf(W0 * phh.y + W1 * ps.y + W2 * pt.y + rb.y) * vv.y
                 + sigmoidf(W0 * phh.z + W1 * ps.z + W2 * pt.z + rb.z) * vv.z
                 + sigmoidf(W0 * phh.w + W1 * ps.w + W2 * pt.w + rb.w) * vv.w;
        sv = g16_sum(sv);
        float om = (sv + cc) * 0.125f;
        if (valid) {
            if (l == 0) omg[j] = om;
            so += om;
        }
    }
    so += __shfl_xor(so, 16, 64);
    so += __shfl_xor(so, 32, 64);
    if (lane == 0) segO[h] = so;
}

// alpha + eta from stored omg/segO (separate dispatch = visibility boundary)
__global__ void k_omega2b(const int* __restrict__ offH, const float* __restrict__ omg,
                          const float* __restrict__ segO, float* __restrict__ csr_a,
                          float* __restrict__ csr_et, int n) {
    int h = (blockIdx.x * blockDim.x + threadIdx.x) >> 6;
    int lane = threadIdx.x & 63;
    if (h >= n) return;
    int s = offH[h], e = offH[h + 1];
    if (s == e) return;
    float invO = 1.0f / (segO[h] + 1e-8f);
    float se = 0.f;
    for (int j = s + lane; j < e; j += 64) {
        float a = omg[j] * invO;
        csr_a[j] = a;
        se += (a > GAMMA) ? a : 0.0f;
    }
    se = wave_sum(se);
    float invE = 1.0f / (se + 1e-8f);
    for (int j = s + lane; j < e; j += 64) {
        float a = csr_a[j];
        csr_et[j] = ((a > GAMMA) ? a : 0.0f) * invE;
    }
}

// ================= fused hop: blocks [0,EB) entity side, rest user side =================
__global__ void k_hop(const int* __restrict__ offH, const int* __restrict__ tr,
                      const float* __restrict__ rho, const float* __restrict__ rel,
                      const int* __restrict__ offU, const int2* __restrict__ itw,
                      const bf16* __restrict__ ecur, bf16* __restrict__ enxt,
                      const float* __restrict__ initE, const float* __restrict__ initU,
                      float* __restrict__ outE, float* __restrict__ outU,
                      int init, int EB) {
    int b = blockIdx.x;
    int lane = threadIdx.x & 63;
    int l = lane & 15, g = lane >> 4;
    int d0 = l * 4;
    if (b < EB) {
        int gw = b * 4 + (threadIdx.x >> 6);
        if (gw >= N_ENT) return;
        int s = offH[gw], e = offH[gw + 1];
        float a0 = 0.f, a1 = 0.f, a2 = 0.f, a3 = 0.f;
        for (int j0 = s; j0 < e; j0 += 4) {
            int j = j0 + g;
            bool valid = j < e;
            int jj = valid ? j : s;
            int pk = tr[jj];
            int t = pk & 0xFFFFF, r = pk >> 20;
            float rh = valid ? rho[jj] : 0.f;
            ushort4 ev = *(const ushort4*)&ecur[(size_t)t * D + d0];
            float4 rl = *(const float4*)&rel[r * D + d0];
            a0 += rh * bits2f(ev.x) * rl.x;
            a1 += rh * bits2f(ev.y) * rl.y;
            a2 += rh * bits2f(ev.z) * rl.z;
            a3 += rh * bits2f(ev.w) * rl.w;
        }
        a0 += __shfl_xor(a0, 16, 64); a0 += __shfl_xor(a0, 32, 64);
        a1 += __shfl_xor(a1, 16, 64); a1 += __shfl_xor(a1, 32, 64);
        a2 += __shfl_xor(a2, 16, 64); a2 += __shfl_xor(a2, 32, 64);
        a3 += __shfl_xor(a3, 16, 64); a3 += __shfl_xor(a3, 32, 64);
        float invd = 1.0f / fmaxf((float)(e - s), 1.0f);
        a0 *= invd; a1 *= invd; a2 *= invd; a3 *= invd;
        float ss = a0 * a0 + a1 * a1 + a2 * a2 + a3 * a3;
        ss = g16_sum(ss);
        float nrm = fmaxf(sqrtf(ss), 1e-8f);
        float y0 = n2n(a0 / nrm), y1 = n2n(a1 / nrm), y2 = n2n(a2 / nrm), y3 = n2n(a3 / nrm);
        if (g == 0) {
            ushort4 st;
            st.x = f2bf_bits(y0); st.y = f2bf_bits(y1); st.z = f2bf_bits(y2); st.w = f2bf_bits(y3);
            *(ushort4*)&enxt[(size_t)gw * D + d0] = st;
            size_t o = (size_t)gw * D + d0;
            float4 prev;
            if (init) prev = *(const float4*)&initE[o];
            else      prev = *(const float4*)&outE[o];
            *(float4*)&outE[o] = make_float4(prev.x + y0, prev.y + y1, prev.z + y2, prev.w + y3);
        }
    } else {
        int gw = (b - EB) * 4 + (threadIdx.x >> 6);
        if (gw >= N_USERS) return;
        int s = offU[gw], e = offU[gw + 1];
        float a0 = 0.f, a1 = 0.f, a2 = 0.f, a3 = 0.f;
        for (int j0 = s; j0 < e; j0 += 4) {
            int j = j0 + g;
            bool valid = j < e;
            int jj = valid ? j : s;
            int2 iw = itw[jj];
            float w = valid ? __int_as_float(iw.y) : 0.f;
            ushort4 ev = *(const ushort4*)&ecur[(size_t)iw.x * D + d0];
            a0 += w * bits2f(ev.x);
            a1 += w * bits2f(ev.y);
            a2 += w * bits2f(ev.z);
            a3 += w * bits2f(ev.w);
        }
        a0 += __shfl_xor(a0, 16, 64); a0 += __shfl_xor(a0, 32, 64);
        a1 += __shfl_xor(a1, 16, 64); a1 += __shfl_xor(a1, 32, 64);
        a2 += __shfl_xor(a2, 16, 64); a2 += __shfl_xor(a2, 32, 64);
        a3 += __shfl_xor(a3, 16, 64); a3 += __shfl_xor(a3, 32, 64);
        float ss = a0 * a0 + a1 * a1 + a2 * a2 + a3 * a3;
        ss = g16_sum(ss);
        float nrm = fmaxf(sqrtf(ss), 1e-8f);
        float y0 = n2n(a0 / nrm), y1 = n2n(a1 / nrm), y2 = n2n(a2 / nrm), y3 = n2n(a3 / nrm);
        if (g == 0) {
            size_t o = (size_t)gw * D + d0;
            float4 prev;
            if (init) prev = *(const float4*)&initU[o];
            else      prev = *(const float4*)&outU[o];
            *(float4*)&outU[o] = make_float4(prev.x + y0, prev.y + y1, prev.z + y2, prev.w + y3);
        }
    }
}

extern "C" void kernel_launch(void* const* d_in, const int* in_sizes, int n_in,
                              void* d_out, int out_size, void* d_ws, size_t ws_size,
                              hipStream_t stream) {
    const float* user_embed = (const float*)d_in[0];
    const float* item_embed = (const float*)d_in[1];
    const float* Wq = (const float*)d_in[2];
    const float* Wk = (const float*)d_in[3];
    const float* Wv = (const float*)d_in[4];
    const float* ent_real = (const float*)d_in[5];
    const float* ent_imag = (const float*)d_in[6];
    const float* rel_real = (const float*)d_in[7];
    const float* rel_imag = (const float*)d_in[8];
    const float* fp_W1 = (const float*)d_in[9];
    const float* fp_b1 = (const float*)d_in[10];
    const float* fp_W2 = (const float*)d_in[11];
    const float* fp_b2 = (const float*)d_in[12];
    const float* rt_W1 = (const float*)d_in[13];
    const float* rt_b1 = (const float*)d_in[14];
    const float* rt_W2 = (const float*)d_in[15];
    const float* rt_b2 = (const float*)d_in[16];
    const float* relation_emb = (const float*)d_in[17];
    const float* user_emb = (const float*)d_in[18];
    const float* entity_emb = (const float*)d_in[19];
    const float* inter_edge_w = (const float*)d_in[20];
    const int* edge_index = (const int*)d_in[21];
    const int* edge_type = (const int*)d_in[22];
    const int* inter_edge = (const int*)d_in[23];
    float* out = (float*)d_out;

    float* W = (float*)d_ws;
    size_t off = 0;
    auto alloc = [&](size_t n) { float* r = W + off; off += n; return r; };
    // persistent floats
    float* omg    = alloc(NE);
    float* w0a    = alloc(NE);
    float* w1a    = alloc(NE);
    float* w2a    = alloc(NE);
    float* exA    = alloc(NEI);
    float* csr_a  = alloc(NE);
    float* csr_et = alloc(NE);
    float* segO   = alloc(N_ENT);
    float* denU   = alloc(N_USERS);
    float* c      = alloc(N_ITEMS);   // c and p adjacent -> single memset
    float* p      = alloc(64);
    float* v2     = alloc(64);
    float* cb     = alloc(64);
    float* RR1    = alloc(10 * D);
    float* PSI    = alloc(10 * D);
    // persistent ints (region starts 8B-aligned)
    if (off & 1) off++;
    int* IW = (int*)(W + off);
    size_t ioff = 0;
    auto ialloc = [&](size_t n) { int* r = IW + ioff; ioff += n; return r; };
    int2* csr_itw = (int2*)ialloc(2 * NEI);   // packed (item, wbits)
    int* csr_tr = ialloc(NE);
    int* offU   = ialloc(N_USERS + 1);
    int* offH   = ialloc(N_ENT + 1);
    int* bcntU  = ialloc(UBK);                // bcntU/bcntH adjacent -> single memset
    int* bcntH  = ialloc(HBK);
    int* bOffU  = ialloc(UBK + 1);
    int* bOffH  = ialloc(HBK + 1);
    int* bcurU  = ialloc(UBK);
    int* bcurH  = ialloc(HBK);
    off += ioff;
    // union region
    float* U = W + off;
    // CSR-build staging (dead before k_proj reuses this region)
    int2* stIW = (int2*)U;                    // NEI packed (item|ul<<24, wbits)
    int*  stTR = (int*)U + 2 * (size_t)NEI;   // NE packed (t | r<<20 | hl<<24)
    // phase A (within EH slot)
    bf16*  IkB = (bf16*)U;
    float* Iv  = U + (size_t)N_ITEMS * 32;
    float* Uq  = Iv + (size_t)N_ITEMS * D;
    // phase B
    float* EH  = U;
    float* ET  = EH + (size_t)N_ENT * D;
    float* PHI = U;                             // overwrites EH after omega1
    // phase C: eA over dead ET slot, eB over dead PHI slot
    bf16* eA = (bf16*)ET;
    bf16* eB = (bf16*)U;

    const int UCH = (NEI + PCHUNK - 1) / PCHUNK;   // 245
    const int HCH = (NE + PCHUNK - 1) / PCHUNK;    // 123
    const int IB = (N_ITEMS + 63) / 64;
    const int UB = (N_USERS + 63) / 64;
    const int EB = (N_ENT + 63) / 64;
    const int OB = (N_ENT + 3) / 4;             // omega wave-blocks
    const int CB = (N_ENT * D) / 1024;          // cvt blocks (exact)
    const int HE = (N_ENT + 3) / 4;
    const int HU = (N_USERS + 3) / 4;

    // ---- CSR build (bucketed 2-pass multisplit) ----
    hipMemsetAsync(bcntU, 0, (UBK + HBK) * 4, stream);
    hipMemsetAsync(c, 0, (N_ITEMS + 64) * 4, stream);
    k_histb<<<UCH + HCH, 256, 0, stream>>>(inter_edge, edge_index, bcntU, bcntH, UCH);
    k_scanb<<<2, 512, 0, stream>>>(bcntU, bOffU, bcurU, bcntH, bOffH, bcurH, offU, offH);
    k_part1<<<UCH + HCH, 256, 0, stream>>>(inter_edge, inter_edge_w, edge_index,
                                           edge_type, bcurU, bcurH, stIW, stTR, UCH);
    k_part2<<<UBK + HBK, 256, 0, stream>>>(bOffU, stIW, offU, csr_itw,
                                           bOffH, stTR, offH, csr_tr, UBK);

    // ---- Phase A ----
    k_proj<<<IB + UB, 256, 0, stream>>>(item_embed, Wk, Wv, user_embed, Wq,
                                        IkB, Iv, Uq, IB);
    k_userA<<<(N_USERS + 3) / 4, 256, 0, stream>>>(offU, csr_itw, Uq, IkB, exA, denU, N_USERS);
    k_userB<<<(N_USERS + 3) / 4, 256, 0, stream>>>(offU, csr_itw, exA, denU, c, N_USERS);
    k_pdense<<<64, 256, 0, stream>>>(c, Iv, p, N_ITEMS);

    // ---- Phase B ----
    k_entabx<<<EB + 2, 256, 0, stream>>>(ent_real, ent_imag, fp_W1, rel_real, rel_imag,
                                         rt_W1, rt_W2, rt_b2, p, EH, ET, RR1, PSI,
                                         v2, cb, EB);
    k_omega1<<<(N_ENT + 3) / 4, 256, 0, stream>>>(offH, csr_tr, EH, ET, RR1, fp_b1,
                                                  fp_W2, fp_b2, w0a, w1a, w2a, N_ENT);
    k_ent_phi<<<EB, 256, 0, stream>>>(ent_real, ent_imag, rt_W1, PHI, N_ENT);
    k_omega2a<<<OB + CB, 256, 0, stream>>>(offH, csr_tr, PHI, PSI, rt_b1, v2, cb,
                                           w0a, w1a, w2a, omg, segO,
                                           entity_emb, eA, OB, N_ENT);
    k_omega2b<<<(N_ENT + 3) / 4, 256, 0, stream>>>(offH, omg, segO, csr_a, csr_et, N_ENT);

    // ---- hops ----
    bf16* ecur = eA;
    bf16* enxt = eB;
    for (int hop = 1; hop <= 3; hop++) {
        const float* rho = (hop < 3) ? csr_a : csr_et;
        int init = (hop == 1) ? 1 : 0;
        k_hop<<<HE + HU, 256, 0, stream>>>(offH, csr_tr, rho, relation_emb,
                                           offU, csr_itw, ecur, enxt,
                                           entity_emb, user_emb,
                                           out, out + (size_t)N_ENT * D, init, HE);
        bf16* tmp = ecur; ecur = enxt; enxt = tmp;
    }
}

// Round 3
// 813.942 us; speedup vs baseline: 1.1310x; 1.0421x over previous
//
#include <hip/hip_runtime.h>
#include <hip/hip_bf16.h>
#include <math.h>

#define N_USERS 50000
#define N_ITEMS 30000
#define N_ENT   100000
#define NE      500000      // KG edges E
#define NEI     1000000     // interaction edges EI
#define D       64
#define GAMMA   0.2f

#define UBK ((N_USERS + 255) / 256)   // 196 user buckets (256 users each)
#define HBK ((N_ENT + 255) / 256)     // 391 head buckets (256 heads each)
#define PCHUNK 4096                   // edges per pass-1 block

typedef __hip_bfloat16 bf16;

__device__ __forceinline__ float wave_sum(float v) {
    #pragma unroll
    for (int off = 32; off > 0; off >>= 1) v += __shfl_xor(v, off, 64);
    return v;
}

__device__ __forceinline__ float g16_sum(float v) {
    #pragma unroll
    for (int off = 1; off < 16; off <<= 1) v += __shfl_xor(v, off, 64);
    return v;
}

__device__ __forceinline__ float bits2f(unsigned short u) {
    return __uint_as_float(((unsigned)u) << 16);
}

__device__ __forceinline__ unsigned short f2bf_bits(float f) {
    bf16 b = __float2bfloat16(f);
    return *(unsigned short*)&b;
}

__device__ __forceinline__ float sigmoidf(float x) { return 1.0f / (1.0f + expf(-x)); }

__device__ __forceinline__ float n2n(float y) {
    if (isnan(y)) return 0.0f;
    if (isinf(y)) return y > 0.0f ? 1e4f : 1e-4f;
    return y;
}

// ================= CSR build: bucketed 2-pass multisplit =================
__global__ __launch_bounds__(256) void k_histb(const int* __restrict__ ie,
        const int* __restrict__ eidx, int* __restrict__ bcntU,
        int* __restrict__ bcntH, int UCH) {
    __shared__ int lc[HBK + 1];
    int t = threadIdx.x;
    int b = blockIdx.x;
    for (int i = t; i < HBK + 1; i += 256) lc[i] = 0;
    __syncthreads();
    if (b < UCH) {
        int base = b * PCHUNK;
        #pragma unroll
        for (int i = 0; i < PCHUNK / 256; i++) {
            int e = base + i * 256 + t;
            if (e < NEI) atomicAdd(&lc[ie[e] >> 8], 1);
        }
        __syncthreads();
        for (int i = t; i < UBK; i += 256) if (lc[i]) atomicAdd(&bcntU[i], lc[i]);
    } else {
        int base = (b - UCH) * PCHUNK;
        #pragma unroll
        for (int i = 0; i < PCHUNK / 256; i++) {
            int e = base + i * 256 + t;
            if (e < NE) atomicAdd(&lc[eidx[e] >> 8], 1);
        }
        __syncthreads();
        for (int i = t; i < HBK; i += 256) if (lc[i]) atomicAdd(&bcntH[i], lc[i]);
    }
}

__global__ void k_scanb(const int* __restrict__ bcntU, int* __restrict__ bOffU,
                        int* __restrict__ bcurU, const int* __restrict__ bcntH,
                        int* __restrict__ bOffH, int* __restrict__ bcurH,
                        int* __restrict__ offU, int* __restrict__ offH) {
    __shared__ int sh[512];
    int t = threadIdx.x;
    const int* c; int* o; int* cu; int n; int tot;
    if (blockIdx.x == 0) { c = bcntU; o = bOffU; cu = bcurU; n = UBK; tot = NEI; }
    else                 { c = bcntH; o = bOffH; cu = bcurH; n = HBK; tot = NE; }
    int v = (t < n) ? c[t] : 0;
    sh[t] = v;
    __syncthreads();
    for (int d = 1; d < 512; d <<= 1) {
        int x = (t >= d) ? sh[t - d] : 0;
        __syncthreads();
        sh[t] += x;
        __syncthreads();
    }
    if (t < n) { int ex = sh[t] - v; o[t] = ex; cu[t] = ex; }
    if (t == 0) {
        o[n] = tot;
        if (blockIdx.x == 0) offU[N_USERS] = NEI;
        else                 offH[N_ENT] = NE;
    }
}

__global__ __launch_bounds__(256) void k_part1(const int* __restrict__ ie,
        const float* __restrict__ w, const int* __restrict__ eidx,
        const int* __restrict__ etype, int* __restrict__ bcurU,
        int* __restrict__ bcurH, int2* __restrict__ stIW,
        int* __restrict__ stTR, int UCH) {
    __shared__ int lcnt[HBK + 1];
    __shared__ int lbase[HBK + 1];
    int t = threadIdx.x;
    int b = blockIdx.x;
    for (int i = t; i < HBK + 1; i += 256) lcnt[i] = 0;
    __syncthreads();
    if (b < UCH) {
        int base = b * PCHUNK;
        int bkt[PCHUNK / 256], rnk[PCHUNK / 256];
        #pragma unroll
        for (int i = 0; i < PCHUNK / 256; i++) {
            int e = base + i * 256 + t;
            bkt[i] = -1;
            rnk[i] = 0;
            if (e < NEI) {
                int k = ie[e] >> 8;
                bkt[i] = k;
                rnk[i] = atomicAdd(&lcnt[k], 1);
            }
        }
        __syncthreads();
        for (int i = t; i < UBK; i += 256)
            if (lcnt[i] > 0) lbase[i] = atomicAdd(&bcurU[i], lcnt[i]);
        __syncthreads();
        #pragma unroll
        for (int i = 0; i < PCHUNK / 256; i++) {
            int e = base + i * 256 + t;
            if (bkt[i] >= 0) {
                int pos = lbase[bkt[i]] + rnk[i];
                int ul = ie[e] & 255;
                stIW[pos] = make_int2(ie[NEI + e] | (ul << 24), __float_as_int(w[e]));
            }
        }
    } else {
        int base = (b - UCH) * PCHUNK;
        int bkt[PCHUNK / 256], rnk[PCHUNK / 256];
        #pragma unroll
        for (int i = 0; i < PCHUNK / 256; i++) {
            int e = base + i * 256 + t;
            bkt[i] = -1;
            rnk[i] = 0;
            if (e < NE) {
                int k = eidx[e] >> 8;
                bkt[i] = k;
                rnk[i] = atomicAdd(&lcnt[k], 1);
            }
        }
        __syncthreads();
        for (int i = t; i < HBK; i += 256)
            if (lcnt[i] > 0) lbase[i] = atomicAdd(&bcurH[i], lcnt[i]);
        __syncthreads();
        #pragma unroll
        for (int i = 0; i < PCHUNK / 256; i++) {
            int e = base + i * 256 + t;
            if (bkt[i] >= 0) {
                int pos = lbase[bkt[i]] + rnk[i];
                int hl = eidx[e] & 255;
                stTR[pos] = eidx[NE + e] | ((etype[e] - 1) << 20) | (hl << 24);
            }
        }
    }
}

__global__ __launch_bounds__(256) void k_part2(const int* __restrict__ bOffU,
        const int2* __restrict__ stIW, int* __restrict__ offU,
        int2* __restrict__ csr_itw, const int* __restrict__ bOffH,
        const int* __restrict__ stTR, int* __restrict__ offH,
        int* __restrict__ csr_tr, int UBKc) {
    __shared__ int lcnt[256];
    __shared__ int lcur[256];
    int t = threadIdx.x;
    int b = blockIdx.x;
    lcnt[t] = 0;
    __syncthreads();
    if (b < UBKc) {
        int s = bOffU[b], e = bOffU[b + 1];
        for (int j = s + t; j < e; j += 256)
            atomicAdd(&lcnt[((unsigned)stIW[j].x) >> 24], 1);
        __syncthreads();
        int v = lcnt[t];
        lcur[t] = v;
        __syncthreads();
        for (int d = 1; d < 256; d <<= 1) {
            int x = (t >= d) ? lcur[t - d] : 0;
            __syncthreads();
            lcur[t] += x;
            __syncthreads();
        }
        int base = s + lcur[t] - v;
        int u = (b << 8) + t;
        if (u < N_USERS) offU[u] = base;
        __syncthreads();
        lcur[t] = base;
        __syncthreads();
        for (int j = s + t; j < e; j += 256) {
            int2 r = stIW[j];
            int pos = atomicAdd(&lcur[((unsigned)r.x) >> 24], 1);
            csr_itw[pos] = make_int2(r.x & 0x00FFFFFF, r.y);
        }
    } else {
        int bb = b - UBKc;
        int s = bOffH[bb], e = bOffH[bb + 1];
        for (int j = s + t; j < e; j += 256)
            atomicAdd(&lcnt[((unsigned)stTR[j]) >> 24], 1);
        __syncthreads();
        int v = lcnt[t];
        lcur[t] = v;
        __syncthreads();
        for (int d = 1; d < 256; d <<= 1) {
            int x = (t >= d) ? lcur[t - d] : 0;
            __syncthreads();
            lcur[t] += x;
            __syncthreads();
        }
        int base = s + lcur[t] - v;
        int h = (bb << 8) + t;
        if (h < N_ENT) offH[h] = base;
        __syncthreads();
        lcur[t] = base;
        __syncthreads();
        for (int j = s + t; j < e; j += 256) {
            int r = stTR[j];
            int pos = atomicAdd(&lcur[((unsigned)r) >> 24], 1);
            csr_tr[pos] = r & 0x00FFFFFF;   // t (20b) + rel (bits 20-23)
        }
    }
}

// ================= lane-owns-row tiled GEMM helpers =================
__device__ __forceinline__ void stage_rows2(const float* __restrict__ s0,
                                            const float* __restrict__ s1,
                                            float* At, int row0, int n, int t) {
    #pragma unroll
    for (int half = 0; half < 2; half++) {
        const float* src = half ? s1 : s0;
        int kofs = half ? 32 : 0;
        #pragma unroll
        for (int fi = t, it = 0; it < 2; fi += 256, it++) {
            int row = fi >> 3;
            int k4 = (fi & 7) << 2;
            float4 v = make_float4(0.f, 0.f, 0.f, 0.f);
            if (row0 + row < n) v = *(const float4*)&src[(size_t)(row0 + row) * 32 + k4];
            At[(kofs + k4 + 0) * 64 + row] = v.x;
            At[(kofs + k4 + 1) * 64 + row] = v.y;
            At[(kofs + k4 + 2) * 64 + row] = v.z;
            At[(kofs + k4 + 3) * 64 + row] = v.w;
        }
    }
}

__device__ __forceinline__ void stage_rows1(const float* __restrict__ src,
                                            float* At, int row0, int n, int t) {
    #pragma unroll
    for (int fi = t, it = 0; it < 4; fi += 256, it++) {
        int row = fi >> 4;
        int k4 = (fi & 15) << 2;
        float4 v = make_float4(0.f, 0.f, 0.f, 0.f);
        if (row0 + row < n) v = *(const float4*)&src[(size_t)(row0 + row) * 64 + k4];
        At[(k4 + 0) * 64 + row] = v.x;
        At[(k4 + 1) * 64 + row] = v.y;
        At[(k4 + 2) * 64 + row] = v.z;
        At[(k4 + 3) * 64 + row] = v.w;
    }
}

__global__ __launch_bounds__(256) void k_proj(const float* __restrict__ I,
        const float* __restrict__ Wk, const float* __restrict__ Wv,
        const float* __restrict__ UE, const float* __restrict__ Wq,
        bf16* __restrict__ IkB, float* __restrict__ Iv, float* __restrict__ Uq, int IB) {
    __shared__ float At[64 * 64];
    int t = threadIdx.x;
    int b = blockIdx.x;
    int lane = t & 63;
    int wv = __builtin_amdgcn_readfirstlane(t >> 6);
    if (b < IB) {
        int row0 = b << 6;
        stage_rows1(I, At, row0, N_ITEMS, t);
        __syncthreads();
        const float* Wb = ((wv >> 1) ? Wv : Wk) + (wv & 1) * 32;
        float acc[32];
        #pragma unroll
        for (int c = 0; c < 32; c++) acc[c] = 0.f;
        for (int k = 0; k < 64; k++) {
            float a = At[k * 64 + lane];
            const float* wr = Wb + k * 64;
            #pragma unroll
            for (int c4 = 0; c4 < 8; c4++) {
                float4 w4 = *(const float4*)&wr[c4 * 4];
                acc[c4 * 4 + 0] += a * w4.x;
                acc[c4 * 4 + 1] += a * w4.y;
                acc[c4 * 4 + 2] += a * w4.z;
                acc[c4 * 4 + 3] += a * w4.w;
            }
        }
        int row = row0 + lane;
        if (row < N_ITEMS) {
            if (wv >> 1) {
                float* dst = Iv + (size_t)row * 64 + (wv & 1) * 32;
                #pragma unroll
                for (int c4 = 0; c4 < 8; c4++)
                    *(float4*)&dst[c4 * 4] = make_float4(acc[c4*4], acc[c4*4+1], acc[c4*4+2], acc[c4*4+3]);
            } else {
                bf16* dst = IkB + (size_t)row * 64 + (wv & 1) * 32;
                #pragma unroll
                for (int c4 = 0; c4 < 8; c4++) {
                    ushort4 s;
                    s.x = f2bf_bits(acc[c4 * 4 + 0]);
                    s.y = f2bf_bits(acc[c4 * 4 + 1]);
                    s.z = f2bf_bits(acc[c4 * 4 + 2]);
                    s.w = f2bf_bits(acc[c4 * 4 + 3]);
                    *(ushort4*)&dst[c4 * 4] = s;
                }
            }
        }
    } else {
        int row0 = (b - IB) << 6;
        stage_rows1(UE, At, row0, N_USERS, t);
        __syncthreads();
        const float* Wb = Wq + wv * 16;
        float acc[16];
        #pragma unroll
        for (int c = 0; c < 16; c++) acc[c] = 0.f;
        for (int k = 0; k < 64; k++) {
            float a = At[k * 64 + lane];
            const float* wr = Wb + k * 64;
            #pragma unroll
            for (int c4 = 0; c4 < 4; c4++) {
                float4 w4 = *(const float4*)&wr[c4 * 4];
                acc[c4 * 4 + 0] += a * w4.x;
                acc[c4 * 4 + 1] += a * w4.y;
                acc[c4 * 4 + 2] += a * w4.z;
                acc[c4 * 4 + 3] += a * w4.w;
            }
        }
        int row = row0 + lane;
        if (row < N_USERS) {
            float* dst = Uq + (size_t)row * 64 + wv * 16;
            #pragma unroll
            for (int c4 = 0; c4 < 4; c4++)
                *(float4*)&dst[c4 * 4] = make_float4(acc[c4*4], acc[c4*4+1], acc[c4*4+2], acc[c4*4+3]);
        }
    }
}

// ================= Stage A edge kernels =================
// 2x unrolled: 8 edges in flight per wave (4 groups x 2 chains)
__global__ __launch_bounds__(256) void k_userA(const int* __restrict__ offU,
                        const int2* __restrict__ itw,
                        const float* __restrict__ Uq, const bf16* __restrict__ IkB,
                        float* __restrict__ exA, float* __restrict__ denU, int n) {
    int u = (blockIdx.x * blockDim.x + threadIdx.x) >> 6;
    int lane = threadIdx.x & 63;
    if (u >= n) return;
    int s = offU[u], e = offU[u + 1];
    if (s == e) return;
    int l = lane & 15, g = lane >> 4;
    float4 qv = *(const float4*)&Uq[(size_t)u * D + l * 4];
    const char* kbase = (const char*)IkB;
    unsigned dby = (unsigned)(l << 3);
    float den = 0.f;
    for (int j0 = s; j0 < e; j0 += 8) {
        int jA = j0 + g, jB = jA + 4;
        bool vA = jA < e, vB = jB < e;
        int2 iA = itw[vA ? jA : s];
        int2 iB = itw[vB ? jB : s];
        ushort4 kA = *(const ushort4*)(kbase + (((unsigned)iA.x) << 7) + dby);
        ushort4 kB = *(const ushort4*)(kbase + (((unsigned)iB.x) << 7) + dby);
        float dA = qv.x * bits2f(kA.x) + qv.y * bits2f(kA.y) +
                   qv.z * bits2f(kA.z) + qv.w * bits2f(kA.w);
        float dB = qv.x * bits2f(kB.x) + qv.y * bits2f(kB.y) +
                   qv.z * bits2f(kB.z) + qv.w * bits2f(kB.w);
        #pragma unroll
        for (int off = 1; off < 16; off <<= 1) {
            dA += __shfl_xor(dA, off, 64);
            dB += __shfl_xor(dB, off, 64);
        }
        float eAv = vA ? expf(dA * 0.125f * __int_as_float(iA.y)) : 0.f;
        float eBv = vB ? expf(dB * 0.125f * __int_as_float(iB.y)) : 0.f;
        den += eAv + eBv;
        if (vA && l == 0) exA[jA] = eAv;
        if (vB && l == 0) exA[jB] = eBv;
    }
    den += __shfl_xor(den, 16, 64);
    den += __shfl_xor(den, 32, 64);
    if (lane == 0) denU[u] = den * (float)(e - s);  // den * deg
}

__global__ void k_userB(const int* __restrict__ offU, const int2* __restrict__ itw,
                        const float* __restrict__ exA, const float* __restrict__ denU,
                        float* __restrict__ c, int n) {
    int u = (blockIdx.x * blockDim.x + threadIdx.x) >> 6;
    int lane = threadIdx.x & 63;
    if (u >= n) return;
    int s = offU[u], e = offU[u + 1];
    if (s == e) return;
    float inv = 1.0f / denU[u];
    for (int j = s + lane; j < e; j += 64)
        atomicAdd(&c[itw[j].x], exA[j] * inv);
}

__global__ void k_pdense(const float* __restrict__ c, const float* __restrict__ Iv,
                         float* __restrict__ p, int n) {
    int lane = threadIdx.x & 63;
    int gw = blockIdx.x * 4 + (threadIdx.x >> 6);
    int nw = gridDim.x * 4;
    float acc = 0.f;
    for (int i = gw; i < n; i += nw) acc += c[i] * Iv[(size_t)i * D + lane];
    __shared__ float red[256];
    red[threadIdx.x] = acc;
    __syncthreads();
    if (threadIdx.x < 64) {
        float s = red[threadIdx.x] + red[threadIdx.x + 64] + red[threadIdx.x + 128] + red[threadIdx.x + 192];
        atomicAdd(&p[threadIdx.x], s);
    }
}

// ================= Stage B =================
__global__ __launch_bounds__(256) void k_entabx(const float* __restrict__ er,
        const float* __restrict__ ei, const float* __restrict__ fpW1,
        const float* __restrict__ rr, const float* __restrict__ ri,
        const float* __restrict__ rtW1, const float* __restrict__ rtW2,
        const float* __restrict__ rt_b2, const float* __restrict__ p,
        float* __restrict__ EH, float* __restrict__ ET,
        float* __restrict__ RR1, float* __restrict__ PSI,
        float* __restrict__ v2, float* __restrict__ cb, int EB) {
    __shared__ float At[64 * 64];
    int b = blockIdx.x;
    int t = threadIdx.x;
    if (b < EB) {
        int row0 = b << 6;
        stage_rows2(er, ei, At, row0, N_ENT, t);
        __syncthreads();
        int lane = t & 63;
        int wv = __builtin_amdgcn_readfirstlane(t >> 6);
        const float* Wb = fpW1 + ((wv >> 1) ? (128 * 64) : 0) + (wv & 1) * 32;
        float acc[32];
        #pragma unroll
        for (int c = 0; c < 32; c++) acc[c] = 0.f;
        for (int k = 0; k < 64; k++) {
            float a = At[k * 64 + lane];
            const float* wr = Wb + k * 64;
            #pragma unroll
            for (int c4 = 0; c4 < 8; c4++) {
                float4 w4 = *(const float4*)&wr[c4 * 4];
                acc[c4 * 4 + 0] += a * w4.x;
                acc[c4 * 4 + 1] += a * w4.y;
                acc[c4 * 4 + 2] += a * w4.z;
                acc[c4 * 4 + 3] += a * w4.w;
            }
        }
        int row = row0 + lane;
        if (row < N_ENT) {
            float* dst = ((wv >> 1) ? ET : EH) + (size_t)row * 64 + (wv & 1) * 32;
            #pragma unroll
            for (int c4 = 0; c4 < 8; c4++)
                *(float4*)&dst[c4 * 4] = make_float4(acc[c4*4], acc[c4*4+1], acc[c4*4+2], acc[c4*4+3]);
        }
    } else if (b == EB) {
        if (t < 64) {
            int lane = t;
            for (int r = 0; r < 10; r++) {
                float a = 0.f, bb = 0.f;
                for (int k = 0; k < 32; k++) {
                    float sr = rr[r * 32 + k], si = ri[r * 32 + k];
                    a  += sr * fpW1[(64 + k) * D + lane] + si * fpW1[(96 + k) * D + lane];
                    bb += sr * rtW1[k * D + lane] + si * rtW1[(32 + k) * D + lane];
                }
                RR1[r * D + lane] = a;
                PSI[r * D + lane] = bb;
            }
        }
    } else {
        if (t < 64) {
            int j = t;
            float acc = 0.f;
            #pragma unroll
            for (int k = 0; k < D; k++) acc += rtW2[j * D + k] * p[k];
            v2[j] = acc;
            float cc = rt_b2[j] * p[j];
            cc = wave_sum(cc);
            if (j == 0) cb[0] = cc;
        }
    }
}

__global__ __launch_bounds__(256) void k_ent_phi(const float* __restrict__ er,
        const float* __restrict__ ei, const float* __restrict__ rtW1,
        float* __restrict__ PHI, int n) {
    __shared__ float At[64 * 64];
    int t = threadIdx.x;
    int row0 = blockIdx.x << 6;
    stage_rows2(er, ei, At, row0, n, t);
    __syncthreads();
    int lane = t & 63;
    int wv = __builtin_amdgcn_readfirstlane(t >> 6);
    const float* Wb = rtW1 + wv * 16;
    float acc[16];
    #pragma unroll
    for (int c = 0; c < 16; c++) acc[c] = 0.f;
    for (int k = 0; k < 64; k++) {
        float a = At[k * 64 + lane];
        const float* wr = Wb + k * 64;
        #pragma unroll
        for (int c4 = 0; c4 < 4; c4++) {
            float4 w4 = *(const float4*)&wr[c4 * 4];
            acc[c4 * 4 + 0] += a * w4.x;
            acc[c4 * 4 + 1] += a * w4.y;
            acc[c4 * 4 + 2] += a * w4.z;
            acc[c4 * 4 + 3] += a * w4.w;
        }
    }
    int row = row0 + lane;
    if (row < n) {
        float* dst = PHI + (size_t)row * 64 + wv * 16;
        #pragma unroll
        for (int c4 = 0; c4 < 4; c4++)
            *(float4*)&dst[c4 * 4] = make_float4(acc[c4*4], acc[c4*4+1], acc[c4*4+2], acc[c4*4+3]);
    }
}

// gate weights -> packed float4 w4a[j]; 2x unrolled
__global__ __launch_bounds__(256) void k_omega1(const int* __restrict__ offH,
                         const int* __restrict__ csr_tr,
                         const float* __restrict__ EH, const float* __restrict__ ET,
                         const float* __restrict__ RR1, const float* __restrict__ fp_b1,
                         const float* __restrict__ fpW2, const float* __restrict__ fp_b2,
                         float4* __restrict__ w4a, int n) {
    int h = (blockIdx.x * blockDim.x + threadIdx.x) >> 6;
    int lane = threadIdx.x & 63;
    if (h >= n) return;
    int s = offH[h], e = offH[h + 1];
    if (s == e) return;
    int l = lane & 15, g = lane >> 4;
    int d0 = l * 4;
    float4 ehh = *(const float4*)&EH[(size_t)h * D + d0];
    float4 b1 = *(const float4*)&fp_b1[d0];
    ehh.x += b1.x; ehh.y += b1.y; ehh.z += b1.z; ehh.w += b1.w;
    float f0[4], f1[4], f2[4];
    #pragma unroll
    for (int cc = 0; cc < 4; cc++) {
        f0[cc] = fpW2[(d0 + cc) * 3 + 0];
        f1[cc] = fpW2[(d0 + cc) * 3 + 1];
        f2[cc] = fpW2[(d0 + cc) * 3 + 2];
    }
    float b20 = fp_b2[0], b21 = fp_b2[1], b22 = fp_b2[2];
    for (int j0 = s; j0 < e; j0 += 8) {
        int jA = j0 + g, jB = jA + 4;
        bool vA = jA < e, vB = jB < e;
        int pkA = csr_tr[vA ? jA : s];
        int pkB = csr_tr[vB ? jB : s];
        int tA = pkA & 0xFFFFF, rA = pkA >> 20;
        int tB = pkB & 0xFFFFF, rB = pkB >> 20;
        float4 etA = *(const float4*)&ET[(size_t)tA * D + d0];
        float4 etB = *(const float4*)&ET[(size_t)tB * D + d0];
        float4 rrA = *(const float4*)&RR1[rA * D + d0];
        float4 rrB = *(const float4*)&RR1[rB * D + d0];
        float zA0 = sigmoidf(ehh.x + rrA.x + etA.x);
        float zA1 = sigmoidf(ehh.y + rrA.y + etA.y);
        float zA2 = sigmoidf(ehh.z + rrA.z + etA.z);
        float zA3 = sigmoidf(ehh.w + rrA.w + etA.w);
        float zB0 = sigmoidf(ehh.x + rrB.x + etB.x);
        float zB1 = sigmoidf(ehh.y + rrB.y + etB.y);
        float zB2 = sigmoidf(ehh.z + rrB.z + etB.z);
        float zB3 = sigmoidf(ehh.w + rrB.w + etB.w);
        float v[6];
        v[0] = zA0 * f0[0] + zA1 * f0[1] + zA2 * f0[2] + zA3 * f0[3];
        v[1] = zA0 * f1[0] + zA1 * f1[1] + zA2 * f1[2] + zA3 * f1[3];
        v[2] = zA0 * f2[0] + zA1 * f2[1] + zA2 * f2[2] + zA3 * f2[3];
        v[3] = zB0 * f0[0] + zB1 * f0[1] + zB2 * f0[2] + zB3 * f0[3];
        v[4] = zB0 * f1[0] + zB1 * f1[1] + zB2 * f1[2] + zB3 * f1[3];
        v[5] = zB0 * f2[0] + zB1 * f2[1] + zB2 * f2[2] + zB3 * f2[3];
        #pragma unroll
        for (int off = 1; off < 16; off <<= 1) {
            #pragma unroll
            for (int q = 0; q < 6; q++) v[q] += __shfl_xor(v[q], off, 64);
        }
        if (vA && l == 0) {
            float a0 = v[0] + b20, a1 = v[1] + b21, a2 = v[2] + b22;
            float mx = fmaxf(a0, fmaxf(a1, a2));
            float e0 = expf(a0 - mx), e1 = expf(a1 - mx), e2 = expf(a2 - mx);
            float inv = 1.0f / (e0 + e1 + e2);
            w4a[jA] = make_float4(e0 * inv, e1 * inv, e2 * inv, 0.f);
        }
        if (vB && l == 0) {
            float a0 = v[3] + b20, a1 = v[4] + b21, a2 = v[5] + b22;
            float mx = fmaxf(a0, fmaxf(a1, a2));
            float e0 = expf(a0 - mx), e1 = expf(a1 - mx), e2 = expf(a2 - mx);
            float inv = 1.0f / (e0 + e1 + e2);
            w4a[jB] = make_float4(e0 * inv, e1 * inv, e2 * inv, 0.f);
        }
    }
}

// omega + segO; cvt blocks appended; 2x unrolled
__global__ __launch_bounds__(256) void k_omega2a(const int* __restrict__ offH,
                          const int* __restrict__ csr_tr,
                          const float* __restrict__ PHI, const float* __restrict__ PSI,
                          const float* __restrict__ rt_b1, const float* __restrict__ v2,
                          const float* __restrict__ cb, const float4* __restrict__ w4a,
                          float* __restrict__ omg, float* __restrict__ segO,
                          const float* __restrict__ src_emb, bf16* __restrict__ eA,
                          int OB, int n) {
    int b = blockIdx.x;
    if (b >= OB) {
        int base = (b - OB) * 1024 + threadIdx.x * 4;
        float4 v = *(const float4*)&src_emb[base];
        ushort4 s;
        s.x = f2bf_bits(v.x); s.y = f2bf_bits(v.y);
        s.z = f2bf_bits(v.z); s.w = f2bf_bits(v.w);
        *(ushort4*)&eA[base] = s;
        return;
    }
    int h = (b * blockDim.x + threadIdx.x) >> 6;
    int lane = threadIdx.x & 63;
    if (h >= n) return;
    int s = offH[h], e = offH[h + 1];
    if (s == e) return;
    int l = lane & 15, g = lane >> 4;
    int d0 = l * 4;
    float4 phh = *(const float4*)&PHI[(size_t)h * D + d0];
    float4 rb = *(const float4*)&rt_b1[d0];
    float4 vv = *(const float4*)&v2[d0];
    float cc = cb[0];
    float so = 0.f;
    for (int j0 = s; j0 < e; j0 += 8) {
        int jA = j0 + g, jB = jA + 4;
        bool vA = jA < e, vB = jB < e;
        int pkA = csr_tr[vA ? jA : s];
        int pkB = csr_tr[vB ? jB : s];
        int tA = pkA & 0xFFFFF, rA = pkA >> 20;
        int tB = pkB & 0xFFFFF, rB = pkB >> 20;
        float4 WA = w4a[vA ? jA : s];
        float4 WB = w4a[vB ? jB : s];
        float4 ptA = *(const float4*)&PHI[(size_t)tA * D + d0];
        float4 ptB = *(const float4*)&PHI[(size_t)tB * D + d0];
        float4 psA = *(const float4*)&PSI[rA * D + d0];
        float4 psB = *(const float4*)&PSI[rB * D + d0];
        float svA = sigmoidf(WA.x * phh.x + WA.y * psA.x + WA.z * ptA.x + rb.x) * vv.x
                  + sigmoidf(WA.x * phh.y + WA.y * psA.y + WA.z * ptA.y + rb.y) * vv.y
                  + sigmoidf(WA.x * phh.z + WA.y * psA.z + WA.z * ptA.z + rb.z) * vv.z
                  + sigmoidf(WA.x * phh.w + WA.y * psA.w + WA.z * ptA.w + rb.w) * vv.w;
        float svB = sigmoidf(WB.x * phh.x + WB.y * psB.x + WB.z * ptB.x + rb.x) * vv.x
                  + sigmoidf(WB.x * phh.y + WB.y * psB.y + WB.z * ptB.y + rb.y) * vv.y
                  + sigmoidf(WB.x * phh.z + WB.y * psB.z + WB.z * ptB.z + rb.z) * vv.z
                  + sigmoidf(WB.x * phh.w + WB.y * psB.w + WB.z * ptB.w + rb.w) * vv.w;
        #pragma unroll
        for (int off = 1; off < 16; off <<= 1) {
            svA += __shfl_xor(svA, off, 64);
            svB += __shfl_xor(svB, off, 64);
        }
        float omA = (svA + cc) * 0.125f;
        float omB = (svB + cc) * 0.125f;
        if (vA) { if (l == 0) omg[jA] = omA; so += omA; }
        if (vB) { if (l == 0) omg[jB] = omB; so += omB; }
    }
    so += __shfl_xor(so, 16, 64);
    so += __shfl_xor(so, 32, 64);
    if (lane == 0) segO[h] = so;
}

// alpha + eta, packed with tr into int2 (pa for alpha-hops, pe for eta-hop)
__global__ __launch_bounds__(256) void k_omega2b(const int* __restrict__ offH,
                          const int* __restrict__ csr_tr,
                          const float* __restrict__ omg,
                          const float* __restrict__ segO, int2* __restrict__ pa,
                          int2* __restrict__ pe, int n) {
    int h = (blockIdx.x * blockDim.x + threadIdx.x) >> 6;
    int lane = threadIdx.x & 63;
    if (h >= n) return;
    int s = offH[h], e = offH[h + 1];
    if (s == e) return;
    float invO = 1.0f / (segO[h] + 1e-8f);
    float se = 0.f;
    for (int j = s + lane; j < e; j += 64) {
        float a = omg[j] * invO;
        pa[j] = make_int2(csr_tr[j], __float_as_int(a));
        se += (a > GAMMA) ? a : 0.0f;
    }
    se = wave_sum(se);
    float invE = 1.0f / (se + 1e-8f);
    for (int j = s + lane; j < e; j += 64) {
        int2 v = pa[j];
        float a = __int_as_float(v.y);
        pe[j] = make_int2(v.x, __float_as_int(((a > GAMMA) ? a : 0.0f) * invE));
    }
}

// ================= fused hop, 2x unrolled, packed (tr,rho) =================
__global__ __launch_bounds__(256) void k_hop(const int* __restrict__ offH,
                      const int2* __restrict__ rt,
                      const float* __restrict__ rel,
                      const int* __restrict__ offU, const int2* __restrict__ itw,
                      const bf16* __restrict__ ecur, bf16* __restrict__ enxt,
                      const float* __restrict__ initE, const float* __restrict__ initU,
                      float* __restrict__ outE, float* __restrict__ outU,
                      int init, int EB) {
    int b = blockIdx.x;
    int lane = threadIdx.x & 63;
    int l = lane & 15, g = lane >> 4;
    int d0 = l * 4;
    const char* ebase = (const char*)ecur;
    unsigned dby = (unsigned)(d0 << 1);
    if (b < EB) {
        int gw = b * 4 + (threadIdx.x >> 6);
        if (gw >= N_ENT) return;
        int s = offH[gw], e = offH[gw + 1];
        float a0 = 0.f, a1 = 0.f, a2 = 0.f, a3 = 0.f;
        for (int j0 = s; j0 < e; j0 += 8) {
            int jA = j0 + g, jB = jA + 4;
            bool vA = jA < e, vB = jB < e;
            int2 pA = rt[vA ? jA : s];
            int2 pB = rt[vB ? jB : s];
            float rhA = vA ? __int_as_float(pA.y) : 0.f;
            float rhB = vB ? __int_as_float(pB.y) : 0.f;
            unsigned tA = (unsigned)pA.x & 0xFFFFFu; int rA = pA.x >> 20;
            unsigned tB = (unsigned)pB.x & 0xFFFFFu; int rB = pB.x >> 20;
            ushort4 evA = *(const ushort4*)(ebase + (tA << 7) + dby);
            ushort4 evB = *(const ushort4*)(ebase + (tB << 7) + dby);
            float4 rlA = *(const float4*)&rel[rA * D + d0];
            float4 rlB = *(const float4*)&rel[rB * D + d0];
            a0 += rhA * bits2f(evA.x) * rlA.x;
            a1 += rhA * bits2f(evA.y) * rlA.y;
            a2 += rhA * bits2f(evA.z) * rlA.z;
            a3 += rhA * bits2f(evA.w) * rlA.w;
            a0 += rhB * bits2f(evB.x) * rlB.x;
            a1 += rhB * bits2f(evB.y) * rlB.y;
            a2 += rhB * bits2f(evB.z) * rlB.z;
            a3 += rhB * bits2f(evB.w) * rlB.w;
        }
        a0 += __shfl_xor(a0, 16, 64); a0 += __shfl_xor(a0, 32, 64);
        a1 += __shfl_xor(a1, 16, 64); a1 += __shfl_xor(a1, 32, 64);
        a2 += __shfl_xor(a2, 16, 64); a2 += __shfl_xor(a2, 32, 64);
        a3 += __shfl_xor(a3, 16, 64); a3 += __shfl_xor(a3, 32, 64);
        float invd = 1.0f / fmaxf((float)(e - s), 1.0f);
        a0 *= invd; a1 *= invd; a2 *= invd; a3 *= invd;
        float ss = a0 * a0 + a1 * a1 + a2 * a2 + a3 * a3;
        ss = g16_sum(ss);
        float nrm = fmaxf(sqrtf(ss), 1e-8f);
        float y0 = n2n(a0 / nrm), y1 = n2n(a1 / nrm), y2 = n2n(a2 / nrm), y3 = n2n(a3 / nrm);
        if (g == 0) {
            ushort4 st;
            st.x = f2bf_bits(y0); st.y = f2bf_bits(y1); st.z = f2bf_bits(y2); st.w = f2bf_bits(y3);
            *(ushort4*)&enxt[(size_t)gw * D + d0] = st;
            size_t o = (size_t)gw * D + d0;
            float4 prev;
            if (init) prev = *(const float4*)&initE[o];
            else      prev = *(const float4*)&outE[o];
            *(float4*)&outE[o] = make_float4(prev.x + y0, prev.y + y1, prev.z + y2, prev.w + y3);
        }
    } else {
        int gw = (b - EB) * 4 + (threadIdx.x >> 6);
        if (gw >= N_USERS) return;
        int s = offU[gw], e = offU[gw + 1];
        float a0 = 0.f, a1 = 0.f, a2 = 0.f, a3 = 0.f;
        for (int j0 = s; j0 < e; j0 += 8) {
            int jA = j0 + g, jB = jA + 4;
            bool vA = jA < e, vB = jB < e;
            int2 iA = itw[vA ? jA : s];
            int2 iB = itw[vB ? jB : s];
            float wA = vA ? __int_as_float(iA.y) : 0.f;
            float wB = vB ? __int_as_float(iB.y) : 0.f;
            ushort4 evA = *(const ushort4*)(ebase + (((unsigned)iA.x) << 7) + dby);
            ushort4 evB = *(const ushort4*)(ebase + (((unsigned)iB.x) << 7) + dby);
            a0 += wA * bits2f(evA.x) + wB * bits2f(evB.x);
            a1 += wA * bits2f(evA.y) + wB * bits2f(evB.y);
            a2 += wA * bits2f(evA.z) + wB * bits2f(evB.z);
            a3 += wA * bits2f(evA.w) + wB * bits2f(evB.w);
        }
        a0 += __shfl_xor(a0, 16, 64); a0 += __shfl_xor(a0, 32, 64);
        a1 += __shfl_xor(a1, 16, 64); a1 += __shfl_xor(a1, 32, 64);
        a2 += __shfl_xor(a2, 16, 64); a2 += __shfl_xor(a2, 32, 64);
        a3 += __shfl_xor(a3, 16, 64); a3 += __shfl_xor(a3, 32, 64);
        float ss = a0 * a0 + a1 * a1 + a2 * a2 + a3 * a3;
        ss = g16_sum(ss);
        float nrm = fmaxf(sqrtf(ss), 1e-8f);
        float y0 = n2n(a0 / nrm), y1 = n2n(a1 / nrm), y2 = n2n(a2 / nrm), y3 = n2n(a3 / nrm);
        if (g == 0) {
            size_t o = (size_t)gw * D + d0;
            float4 prev;
            if (init) prev = *(const float4*)&initU[o];
            else      prev = *(const float4*)&outU[o];
            *(float4*)&outU[o] = make_float4(prev.x + y0, prev.y + y1, prev.z + y2, prev.w + y3);
        }
    }
}

extern "C" void kernel_launch(void* const* d_in, const int* in_sizes, int n_in,
                              void* d_out, int out_size, void* d_ws, size_t ws_size,
                              hipStream_t stream) {
    const float* user_embed = (const float*)d_in[0];
    const float* item_embed = (const float*)d_in[1];
    const float* Wq = (const float*)d_in[2];
    const float* Wk = (const float*)d_in[3];
    const float* Wv = (const float*)d_in[4];
    const float* ent_real = (const float*)d_in[5];
    const float* ent_imag = (const float*)d_in[6];
    const float* rel_real = (const float*)d_in[7];
    const float* rel_imag = (const float*)d_in[8];
    const float* fp_W1 = (const float*)d_in[9];
    const float* fp_b1 = (const float*)d_in[10];
    const float* fp_W2 = (const float*)d_in[11];
    const float* fp_b2 = (const float*)d_in[12];
    const float* rt_W1 = (const float*)d_in[13];
    const float* rt_b1 = (const float*)d_in[14];
    const float* rt_W2 = (const float*)d_in[15];
    const float* rt_b2 = (const float*)d_in[16];
    const float* relation_emb = (const float*)d_in[17];
    const float* user_emb = (const float*)d_in[18];
    const float* entity_emb = (const float*)d_in[19];
    const float* inter_edge_w = (const float*)d_in[20];
    const int* edge_index = (const int*)d_in[21];
    const int* edge_type = (const int*)d_in[22];
    const int* inter_edge = (const int*)d_in[23];
    float* out = (float*)d_out;

    float* W = (float*)d_ws;
    size_t off = 0;
    auto alloc = [&](size_t n) { float* r = W + off; off += n; return r; };
    // persistent floats (w4a first: 16B-aligned)
    float* w4a_f  = alloc(4 * (size_t)NE);   // float4 per edge
    float* omg    = alloc(NE);
    float* exA    = alloc(NEI);
    float* segO   = alloc(N_ENT);
    float* denU   = alloc(N_USERS);
    float* c      = alloc(N_ITEMS);   // c and p adjacent -> single memset
    float* p      = alloc(64);
    float* v2     = alloc(64);
    float* cb     = alloc(64);
    float* RR1    = alloc(10 * D);
    float* PSI    = alloc(10 * D);
    float4* w4a   = (float4*)w4a_f;
    // persistent ints
    off = (off + 3) & ~(size_t)3;
    int* IW = (int*)(W + off);
    size_t ioff = 0;
    auto ialloc = [&](size_t n) { int* r = IW + ioff; ioff += n; return r; };
    int2* csr_itw = (int2*)ialloc(2 * (size_t)NEI);   // packed (item, wbits)
    int2* pa      = (int2*)ialloc(2 * (size_t)NE);    // packed (tr, alpha)
    int2* pe      = (int2*)ialloc(2 * (size_t)NE);    // packed (tr, eta)
    int* csr_tr = ialloc(NE);
    int* offU   = ialloc(N_USERS + 1);
    int* offH   = ialloc(N_ENT + 1);
    int* bcntU  = ialloc(UBK);                // bcntU/bcntH adjacent -> single memset
    int* bcntH  = ialloc(HBK);
    int* bOffU  = ialloc(UBK + 1);
    int* bOffH  = ialloc(HBK + 1);
    int* bcurU  = ialloc(UBK);
    int* bcurH  = ialloc(HBK);
    off += ioff;
    off = (off + 3) & ~(size_t)3;
    // union region
    float* U = W + off;
    // CSR-build staging (dead before k_proj reuses this region)
    int2* stIW = (int2*)U;                    // NEI packed (item|ul<<24, wbits)
    int*  stTR = (int*)U + 2 * (size_t)NEI;   // NE packed (t | r<<20 | hl<<24)
    // phase A
    bf16*  IkB = (bf16*)U;
    float* Iv  = U + (size_t)N_ITEMS * 32;
    float* Uq  = Iv + (size_t)N_ITEMS * D;
    // phase B
    float* EH  = U;
    float* ET  = EH + (size_t)N_ENT * D;
    float* PHI = U;                             // overwrites EH after omega1
    // phase C
    bf16* eA = (bf16*)ET;
    bf16* eB = (bf16*)U;

    const int UCH = (NEI + PCHUNK - 1) / PCHUNK;   // 245
    const int HCH = (NE + PCHUNK - 1) / PCHUNK;    // 123
    const int IB = (N_ITEMS + 63) / 64;
    const int UB = (N_USERS + 63) / 64;
    const int EB = (N_ENT + 63) / 64;
    const int OB = (N_ENT + 3) / 4;             // omega wave-blocks
    const int CB = (N_ENT * D) / 1024;          // cvt blocks (exact)
    const int HE = (N_ENT + 3) / 4;
    const int HU = (N_USERS + 3) / 4;

    // ---- CSR build (bucketed 2-pass multisplit) ----
    hipMemsetAsync(bcntU, 0, (UBK + HBK) * 4, stream);
    hipMemsetAsync(c, 0, (N_ITEMS + 64) * 4, stream);
    k_histb<<<UCH + HCH, 256, 0, stream>>>(inter_edge, edge_index, bcntU, bcntH, UCH);
    k_scanb<<<2, 512, 0, stream>>>(bcntU, bOffU, bcurU, bcntH, bOffH, bcurH, offU, offH);
    k_part1<<<UCH + HCH, 256, 0, stream>>>(inter_edge, inter_edge_w, edge_index,
                                           edge_type, bcurU, bcurH, stIW, stTR, UCH);
    k_part2<<<UBK + HBK, 256, 0, stream>>>(bOffU, stIW, offU, csr_itw,
                                           bOffH, stTR, offH, csr_tr, UBK);

    // ---- Phase A ----
    k_proj<<<IB + UB, 256, 0, stream>>>(item_embed, Wk, Wv, user_embed, Wq,
                                        IkB, Iv, Uq, IB);
    k_userA<<<(N_USERS + 3) / 4, 256, 0, stream>>>(offU, csr_itw, Uq, IkB, exA, denU, N_USERS);
    k_userB<<<(N_USERS + 3) / 4, 256, 0, stream>>>(offU, csr_itw, exA, denU, c, N_USERS);
    k_pdense<<<64, 256, 0, stream>>>(c, Iv, p, N_ITEMS);

    // ---- Phase B ----
    k_entabx<<<EB + 2, 256, 0, stream>>>(ent_real, ent_imag, fp_W1, rel_real, rel_imag,
                                         rt_W1, rt_W2, rt_b2, p, EH, ET, RR1, PSI,
                                         v2, cb, EB);
    k_omega1<<<(N_ENT + 3) / 4, 256, 0, stream>>>(offH, csr_tr, EH, ET, RR1, fp_b1,
                                                  fp_W2, fp_b2, w4a, N_ENT);
    k_ent_phi<<<EB, 256, 0, stream>>>(ent_real, ent_imag, rt_W1, PHI, N_ENT);
    k_omega2a<<<OB + CB, 256, 0, stream>>>(offH, csr_tr, PHI, PSI, rt_b1, v2, cb,
                                           w4a, omg, segO,
                                           entity_emb, eA, OB, N_ENT);
    k_omega2b<<<(N_ENT + 3) / 4, 256, 0, stream>>>(offH, csr_tr, omg, segO, pa, pe, N_ENT);

    // ---- hops ----
    bf16* ecur = eA;
    bf16* enxt = eB;
    for (int hop = 1; hop <= 3; hop++) {
        const int2* rt = (hop < 3) ? pa : pe;
        int init = (hop == 1) ? 1 : 0;
        k_hop<<<HE + HU, 256, 0, stream>>>(offH, rt, relation_emb,
                                           offU, csr_itw, ecur, enxt,
                                           entity_emb, user_emb,
                                           out, out + (size_t)N_ENT * D, init, HE);
        bf16* tmp = ecur; ecur = enxt; enxt = tmp;
    }
}